// Round 1
// baseline (2813.028 us; speedup 1.0000x reference)
//
#include <hip/hip_runtime.h>
#include <hip/hip_bf16.h>
#include <math.h>

#define D 128
#define LRELU_SLOPE 0.2f

__device__ __forceinline__ float lrelu(float x){ return x > 0.f ? x : LRELU_SLOPE * x; }

// ---------------- CSR build (dst-indexed) ----------------
__global__ void count_kernel(const int* __restrict__ dst, int E, int* __restrict__ counts){
  int e = blockIdx.x*blockDim.x + threadIdx.x;
  if (e < E) atomicAdd(&counts[dst[e]], 1);
}

__global__ __launch_bounds__(1024) void scan_kernel(const int* __restrict__ counts,
                                                    int* __restrict__ row_ptr,
                                                    int* __restrict__ cursor, int n){
  __shared__ int sums[1024];
  int t = threadIdx.x;
  int seg = (n + 1023) >> 10;
  int beg = t*seg;
  int end = beg + seg;
  if (end > n) end = n;
  if (beg > n) beg = n;
  int s = 0;
  for (int i = beg; i < end; ++i) s += counts[i];
  sums[t] = s;
  __syncthreads();
  // Hillis-Steele inclusive scan (read-all then write-all per round)
  for (int d = 1; d < 1024; d <<= 1){
    int add = (t >= d) ? sums[t-d] : 0;
    __syncthreads();
    sums[t] += add;
    __syncthreads();
  }
  int run = sums[t] - s;  // exclusive prefix for this thread's segment
  for (int i = beg; i < end; ++i){
    row_ptr[i] = run;
    cursor[i]  = run;
    run += counts[i];
  }
  if (t == 1023) row_ptr[n] = sums[1023];
}

__global__ void scatter_kernel(const int* __restrict__ src, const int* __restrict__ dst,
                               int E, int* __restrict__ cursor, int* __restrict__ col){
  int e = blockIdx.x*blockDim.x + threadIdx.x;
  if (e < E){
    int d = dst[e];
    int pos = atomicAdd(&cursor[d], 1);
    col[pos] = src[e];
  }
}

// ---------------- fused GEMM (H = X @ W) + attention logits ----------------
// Block: 256 threads. tc = tid%32 -> cols 4*tc..4*tc+3 ; tr = tid/32 -> rows 8*tr..8*tr+7
// Block tile: 64 rows x 128 cols. W (64KB) + X tile (32KB) in LDS.
__global__ __launch_bounds__(256) void gemm_al_kernel(const float* __restrict__ X,
    const float* __restrict__ W, const float* __restrict__ a_src, const float* __restrict__ a_dst,
    float* __restrict__ H, float* __restrict__ ALs, float* __restrict__ ALd,
    int n, int ntiles)
{
  __shared__ float Ws[D*D];      // 64 KB
  __shared__ float Xs[64*D];     // 32 KB
  int tid = threadIdx.x;
  int tc = tid & 31;
  int tr = tid >> 5;

  for (int i = tid; i < D*D/4; i += 256)
    ((float4*)Ws)[i] = ((const float4*)W)[i];

  float4 as4 = ((const float4*)a_src)[tc];
  float4 ad4 = ((const float4*)a_dst)[tc];

  for (int tile = blockIdx.x; tile < ntiles; tile += gridDim.x){
    __syncthreads();   // protect Xs (and Ws on first iter)
    for (int i = tid; i < 64*D/4; i += 256){
      int r = i >> 5;           // 32 float4 per row
      int gr = tile*64 + r;
      float4 v = make_float4(0.f,0.f,0.f,0.f);
      if (gr < n) v = ((const float4*)(X + (size_t)gr*D))[i & 31];
      ((float4*)Xs)[i] = v;
    }
    __syncthreads();

    float acc[8][4];
    #pragma unroll
    for (int r=0;r<8;++r){ acc[r][0]=0.f; acc[r][1]=0.f; acc[r][2]=0.f; acc[r][3]=0.f; }

    for (int k = 0; k < D; k += 4){
      float4 xr[8];
      #pragma unroll
      for (int r=0;r<8;++r)
        xr[r] = *(const float4*)&Xs[(tr*8+r)*D + k];
      #pragma unroll
      for (int kk=0;kk<4;++kk){
        float4 w4 = *(const float4*)&Ws[(k+kk)*D + tc*4];
        #pragma unroll
        for (int r=0;r<8;++r){
          float xv = (kk==0)?xr[r].x:(kk==1)?xr[r].y:(kk==2)?xr[r].z:xr[r].w;
          acc[r][0] += xv*w4.x; acc[r][1] += xv*w4.y;
          acc[r][2] += xv*w4.z; acc[r][3] += xv*w4.w;
        }
      }
    }

    #pragma unroll
    for (int r=0;r<8;++r){
      int gr = tile*64 + tr*8 + r;
      bool ok = gr < n;
      if (ok){
        float4 o; o.x=acc[r][0]; o.y=acc[r][1]; o.z=acc[r][2]; o.w=acc[r][3];
        ((float4*)(H + (size_t)gr*D))[tc] = o;
      }
      float ps = acc[r][0]*as4.x + acc[r][1]*as4.y + acc[r][2]*as4.z + acc[r][3]*as4.w;
      float pd = acc[r][0]*ad4.x + acc[r][1]*ad4.y + acc[r][2]*ad4.z + acc[r][3]*ad4.w;
      #pragma unroll
      for (int off=16; off>=1; off>>=1){
        ps += __shfl_xor(ps, off);
        pd += __shfl_xor(pd, off);
      }
      if (tc == 0 && ok){ ALs[gr] = ps; ALd[gr] = pd; }
    }
  }
}

// ---------------- per-dst online-softmax aggregation ----------------
// One wave (64 lanes) per destination node; 2 floats per lane (D=128).
// Self-loop is the init term: m = e_self, z = 1, acc = h[i].
__global__ __launch_bounds__(256) void agg_kernel(const float* __restrict__ H,
    const float* __restrict__ ALs, const float* __restrict__ ALd,
    const int* __restrict__ row_ptr, const int* __restrict__ col,
    const float* __restrict__ bias, float* __restrict__ out, int n)
{
  int gtid = blockIdx.x*blockDim.x + threadIdx.x;
  int node = gtid >> 6;
  int lane = gtid & 63;
  if (node >= n) return;

  int beg = row_ptr[node], end = row_ptr[node+1];
  float ald = ALd[node];
  const float2* H2 = (const float2*)H;

  float2 acc = H2[(size_t)node*64 + lane];   // self-loop h[i]
  float m = lrelu(ALs[node] + ald);          // e_self
  float z = 1.f;

  int s_next = (beg < end) ? col[beg] : 0;
  for (int j = beg; j < end; ++j){
    int s = s_next;
    if (j+1 < end) s_next = col[j+1];
    float e = lrelu(ALs[s] + ald);
    float2 hs = H2[(size_t)s*64 + lane];
    float w;
    if (e > m){                       // wave-uniform branch (scalar state)
      float sc = __expf(m - e);
      z *= sc; acc.x *= sc; acc.y *= sc;
      m = e; w = 1.f;
    } else {
      w = __expf(e - m);
    }
    z += w;
    acc.x += w*hs.x; acc.y += w*hs.y;
  }
  float inv = 1.f / z;
  float2 b2 = ((const float2*)bias)[lane];
  float2 o; o.x = acc.x*inv + b2.x; o.y = acc.y*inv + b2.y;
  ((float2*)out)[(size_t)node*64 + lane] = o;
}

// ---------------- launch ----------------
extern "C" void kernel_launch(void* const* d_in, const int* in_sizes, int n_in,
                              void* d_out, int out_size, void* d_ws, size_t ws_size,
                              hipStream_t stream)
{
  const float* x   = (const float*)d_in[0];
  const int*   ei  = (const int*)  d_in[1];
  const float* W1  = (const float*)d_in[2];
  const float* as1 = (const float*)d_in[3];
  const float* ad1 = (const float*)d_in[4];
  const float* b1  = (const float*)d_in[5];
  const float* W2  = (const float*)d_in[6];
  const float* as2 = (const float*)d_in[7];
  const float* ad2 = (const float*)d_in[8];
  const float* b2  = (const float*)d_in[9];

  int n = in_sizes[0] / D;
  int E = in_sizes[1] / 2;
  const int* src = ei;
  const int* dst = ei + E;

  // workspace layout (~60 MB)
  float* h   = (float*)d_ws;                 // n*D
  float* als = h + (size_t)n*D;              // n
  float* ald = als + n;                      // n
  int* row_ptr = (int*)(ald + n);            // n+1
  int* cursor  = row_ptr + (n+1);            // n
  int* counts  = cursor + n;                 // n
  int* col     = counts + n;                 // E

  float* out = (float*)d_out;

  hipMemsetAsync(counts, 0, (size_t)n*sizeof(int), stream);
  int eb = (E + 255)/256;
  count_kernel  <<<eb, 256, 0, stream>>>(dst, E, counts);
  scan_kernel   <<<1, 1024, 0, stream>>>(counts, row_ptr, cursor, n);
  scatter_kernel<<<eb, 256, 0, stream>>>(src, dst, E, cursor, col);

  int ntiles = (n + 63)/64;
  int aggblocks = (int)(((size_t)n*64 + 255)/256);

  gemm_al_kernel<<<256, 256, 0, stream>>>(x,  W1, as1, ad1, h, als, ald, n, ntiles);
  agg_kernel    <<<aggblocks, 256, 0, stream>>>(h, als, ald, row_ptr, col, b1, out, n);
  gemm_al_kernel<<<256, 256, 0, stream>>>(out, W2, as2, ad2, h, als, ald, n, ntiles);
  agg_kernel    <<<aggblocks, 256, 0, stream>>>(h, als, ald, row_ptr, col, b2, out, n);
}

// Round 2
// 814.462 us; speedup vs baseline: 3.4538x; 3.4538x over previous
//
#include <hip/hip_runtime.h>
#include <hip/hip_bf16.h>
#include <math.h>

#define D 128
#define LRELU_SLOPE 0.2f

typedef __attribute__((ext_vector_type(8))) short bf16x8;
typedef __attribute__((ext_vector_type(4))) float f32x4;

__device__ __forceinline__ float lrelu(float x){ return x > 0.f ? x : LRELU_SLOPE * x; }

__device__ __forceinline__ unsigned short bf16_rn(float x){
  unsigned int u = __float_as_uint(x);
  return (unsigned short)((u + 0x7FFFu + ((u >> 16) & 1u)) >> 16);
}

// ---------------- CSR build (dst-indexed) ----------------
__global__ void count_kernel(const int* __restrict__ dst, int E, int* __restrict__ counts){
  int e = blockIdx.x*blockDim.x + threadIdx.x;
  if (e < E) atomicAdd(&counts[dst[e]], 1);
}

__global__ __launch_bounds__(1024) void scan_kernel(const int* __restrict__ counts,
                                                    int* __restrict__ row_ptr,
                                                    int* __restrict__ cursor, int n){
  __shared__ int sums[1024];
  int t = threadIdx.x;
  int seg = (n + 1023) >> 10;
  int beg = t*seg;
  int end = beg + seg;
  if (end > n) end = n;
  if (beg > n) beg = n;
  int s = 0;
  for (int i = beg; i < end; ++i) s += counts[i];
  sums[t] = s;
  __syncthreads();
  for (int d = 1; d < 1024; d <<= 1){
    int add = (t >= d) ? sums[t-d] : 0;
    __syncthreads();
    sums[t] += add;
    __syncthreads();
  }
  int run = sums[t] - s;
  for (int i = beg; i < end; ++i){
    row_ptr[i] = run;
    cursor[i]  = run;
    run += counts[i];
  }
  if (t == 1023) row_ptr[n] = sums[1023];
}

__global__ void scatter_kernel(const int* __restrict__ src, const int* __restrict__ dst,
                               int E, int* __restrict__ cursor, int* __restrict__ col){
  int e = blockIdx.x*blockDim.x + threadIdx.x;
  if (e < E){
    int d = dst[e];
    int pos = atomicAdd(&cursor[d], 1);
    col[pos] = src[e];
  }
}

// ---------------- MFMA bf16 split-precision GEMM + attention logits ----------------
// H = X @ W (M=n rows, N=K=128), 3-term split: xh*wh + xl*wh + xh*wl  (~fp32 accurate)
// Block: 256 threads (4 waves). Tile: 128 rows x 128 cols, full K=128 staged in LDS.
// LDS layout: [row][128] bf16, XOR-swizzled in 8-element (16B) groups:
//   element (r,c) stored at group ((c>>3) ^ (r&7)), giving conflict-free ds_read_b128.
__global__ __launch_bounds__(256) void gemm_al_kernel(const float* __restrict__ X,
    const float* __restrict__ W, const float* __restrict__ a_src, const float* __restrict__ a_dst,
    float* __restrict__ H, float* __restrict__ ALs, float* __restrict__ ALd, int n)
{
  __shared__ unsigned short Xh[128*128];   // 32 KB
  __shared__ unsigned short Xl[128*128];   // 32 KB
  __shared__ unsigned short Wh[128*128];   // 32 KB (W transposed: [n][k])
  __shared__ unsigned short Wl[128*128];   // 32 KB
  int tid  = threadIdx.x;
  int lane = tid & 63;
  int wave = tid >> 6;
  int row0 = blockIdx.x * 128;

  // ---- stage W: read row-major W[k][n], write transposed+split+swizzled Wt[n][k] ----
  {
    int nn   = tid & 127;
    int half = tid >> 7;           // 0..1
    int swz  = nn & 7;
    #pragma unroll 4
    for (int kk = 0; kk < 64; ++kk){
      int k = half*64 + kk;
      float w = W[k*D + nn];       // lanes: consecutive nn, same k -> coalesced
      unsigned short h = bf16_rn(w);
      float wh = __uint_as_float(((unsigned int)h) << 16);
      unsigned short l = bf16_rn(w - wh);
      int idx = nn*128 + (((k>>3) ^ swz) << 3) + (k & 7);
      Wh[idx] = h; Wl[idx] = l;
    }
  }
  // ---- stage X tile: coalesced float4 reads, split, swizzled packed writes ----
  {
    #pragma unroll 4
    for (int it = 0; it < 16; ++it){
      int f  = it*256 + tid;       // 0..4095
      int r  = f >> 5;             // 0..127
      int c4 = f & 31;             // float4 index within row
      float4 v = make_float4(0.f,0.f,0.f,0.f);
      int gr = row0 + r;
      if (gr < n) v = ((const float4*)(X + (size_t)gr*D))[c4];
      unsigned short h0 = bf16_rn(v.x);
      unsigned short h1 = bf16_rn(v.y);
      unsigned short h2 = bf16_rn(v.z);
      unsigned short h3 = bf16_rn(v.w);
      unsigned short l0 = bf16_rn(v.x - __uint_as_float(((unsigned)h0)<<16));
      unsigned short l1 = bf16_rn(v.y - __uint_as_float(((unsigned)h1)<<16));
      unsigned short l2 = bf16_rn(v.z - __uint_as_float(((unsigned)h2)<<16));
      unsigned short l3 = bf16_rn(v.w - __uint_as_float(((unsigned)h3)<<16));
      int g   = (c4 >> 1) ^ (r & 7);
      int idx = r*128 + (g << 3) + ((c4 & 1) << 2);
      *(uint2*)&Xh[idx] = make_uint2((unsigned)h0 | ((unsigned)h1<<16),
                                     (unsigned)h2 | ((unsigned)h3<<16));
      *(uint2*)&Xl[idx] = make_uint2((unsigned)l0 | ((unsigned)l1<<16),
                                     (unsigned)l2 | ((unsigned)l3<<16));
    }
  }
  __syncthreads();

  int l15 = lane & 15;
  int l4  = lane >> 4;

  f32x4 acc[2][8];
  #pragma unroll
  for (int rf = 0; rf < 2; ++rf)
    #pragma unroll
    for (int cf = 0; cf < 8; ++cf)
      acc[rf][cf] = (f32x4){0.f, 0.f, 0.f, 0.f};

  #pragma unroll
  for (int kc = 0; kc < 4; ++kc){
    int g = kc*4 + l4;             // k-group 0..15 for this lane
    bf16x8 ah[2], al[2];
    #pragma unroll
    for (int rf = 0; rf < 2; ++rf){
      int r   = wave*32 + rf*16 + l15;
      int idx = r*128 + ((g ^ (r & 7)) << 3);
      ah[rf] = *(const bf16x8*)&Xh[idx];
      al[rf] = *(const bf16x8*)&Xl[idx];
    }
    #pragma unroll
    for (int cf = 0; cf < 8; ++cf){
      int nn  = cf*16 + l15;
      int idx = nn*128 + ((g ^ (nn & 7)) << 3);
      bf16x8 bh = *(const bf16x8*)&Wh[idx];
      bf16x8 bl = *(const bf16x8*)&Wl[idx];
      #pragma unroll
      for (int rf = 0; rf < 2; ++rf){
        acc[rf][cf] = __builtin_amdgcn_mfma_f32_16x16x32_bf16(ah[rf], bh, acc[rf][cf], 0, 0, 0);
        acc[rf][cf] = __builtin_amdgcn_mfma_f32_16x16x32_bf16(al[rf], bh, acc[rf][cf], 0, 0, 0);
        acc[rf][cf] = __builtin_amdgcn_mfma_f32_16x16x32_bf16(ah[rf], bl, acc[rf][cf], 0, 0, 0);
      }
    }
  }

  // ---- epilogue: store H + attention logits ----
  float as_c[8], ad_c[8];
  #pragma unroll
  for (int cf = 0; cf < 8; ++cf){
    as_c[cf] = a_src[cf*16 + l15];
    ad_c[cf] = a_dst[cf*16 + l15];
  }

  #pragma unroll
  for (int rf = 0; rf < 2; ++rf){
    #pragma unroll
    for (int reg = 0; reg < 4; ++reg){
      int gr = row0 + wave*32 + rf*16 + l4*4 + reg;   // C/D: row=(lane>>4)*4+reg
      bool ok = gr < n;
      if (ok){
        #pragma unroll
        for (int cf = 0; cf < 8; ++cf)
          H[(size_t)gr*D + cf*16 + l15] = acc[rf][cf][reg];  // col = lane&15
      }
      float ps = 0.f, pd = 0.f;
      #pragma unroll
      for (int cf = 0; cf < 8; ++cf){
        ps += acc[rf][cf][reg] * as_c[cf];
        pd += acc[rf][cf][reg] * ad_c[cf];
      }
      ps += __shfl_xor(ps, 1); pd += __shfl_xor(pd, 1);
      ps += __shfl_xor(ps, 2); pd += __shfl_xor(pd, 2);
      ps += __shfl_xor(ps, 4); pd += __shfl_xor(pd, 4);
      ps += __shfl_xor(ps, 8); pd += __shfl_xor(pd, 8);
      if (l15 == 0 && ok){ ALs[gr] = ps; ALd[gr] = pd; }
    }
  }
}

// ---------------- per-dst online-softmax aggregation ----------------
__global__ __launch_bounds__(256) void agg_kernel(const float* __restrict__ H,
    const float* __restrict__ ALs, const float* __restrict__ ALd,
    const int* __restrict__ row_ptr, const int* __restrict__ col,
    const float* __restrict__ bias, float* __restrict__ out, int n)
{
  int gtid = blockIdx.x*blockDim.x + threadIdx.x;
  int node = gtid >> 6;
  int lane = gtid & 63;
  if (node >= n) return;

  int beg = row_ptr[node], end = row_ptr[node+1];
  float ald = ALd[node];
  const float2* H2 = (const float2*)H;

  float2 acc = H2[(size_t)node*64 + lane];   // self-loop h[i]
  float m = lrelu(ALs[node] + ald);          // e_self
  float z = 1.f;

  int s_next = (beg < end) ? col[beg] : 0;
  for (int j = beg; j < end; ++j){
    int s = s_next;
    if (j+1 < end) s_next = col[j+1];
    float e = lrelu(ALs[s] + ald);
    float2 hs = H2[(size_t)s*64 + lane];
    float w;
    if (e > m){                       // wave-uniform branch (scalar state)
      float sc = __expf(m - e);
      z *= sc; acc.x *= sc; acc.y *= sc;
      m = e; w = 1.f;
    } else {
      w = __expf(e - m);
    }
    z += w;
    acc.x += w*hs.x; acc.y += w*hs.y;
  }
  float inv = 1.f / z;
  float2 b2 = ((const float2*)bias)[lane];
  float2 o; o.x = acc.x*inv + b2.x; o.y = acc.y*inv + b2.y;
  ((float2*)out)[(size_t)node*64 + lane] = o;
}

// ---------------- launch ----------------
extern "C" void kernel_launch(void* const* d_in, const int* in_sizes, int n_in,
                              void* d_out, int out_size, void* d_ws, size_t ws_size,
                              hipStream_t stream)
{
  const float* x   = (const float*)d_in[0];
  const int*   ei  = (const int*)  d_in[1];
  const float* W1  = (const float*)d_in[2];
  const float* as1 = (const float*)d_in[3];
  const float* ad1 = (const float*)d_in[4];
  const float* b1  = (const float*)d_in[5];
  const float* W2  = (const float*)d_in[6];
  const float* as2 = (const float*)d_in[7];
  const float* ad2 = (const float*)d_in[8];
  const float* b2  = (const float*)d_in[9];

  int n = in_sizes[0] / D;
  int E = in_sizes[1] / 2;
  const int* src = ei;
  const int* dst = ei + E;

  // workspace layout
  float* h   = (float*)d_ws;                 // n*D
  float* als = h + (size_t)n*D;              // n
  float* ald = als + n;                      // n
  int* row_ptr = (int*)(ald + n);            // n+1
  int* cursor  = row_ptr + (n+1);            // n
  int* counts  = cursor + n;                 // n
  int* col     = counts + n;                 // E

  float* out = (float*)d_out;

  hipMemsetAsync(counts, 0, (size_t)n*sizeof(int), stream);
  int eb = (E + 255)/256;
  count_kernel  <<<eb, 256, 0, stream>>>(dst, E, counts);
  scan_kernel   <<<1, 1024, 0, stream>>>(counts, row_ptr, cursor, n);
  scatter_kernel<<<eb, 256, 0, stream>>>(src, dst, E, cursor, col);

  int ntiles = (n + 127)/128;
  int aggblocks = (int)(((size_t)n*64 + 255)/256);

  gemm_al_kernel<<<ntiles, 256, 0, stream>>>(x,  W1, as1, ad1, h, als, ald, n);
  agg_kernel    <<<aggblocks, 256, 0, stream>>>(h, als, ald, row_ptr, col, b1, out, n);
  gemm_al_kernel<<<ntiles, 256, 0, stream>>>(out, W2, as2, ad2, h, als, ald, n);
  agg_kernel    <<<aggblocks, 256, 0, stream>>>(h, als, ald, row_ptr, col, b2, out, n);
}

// Round 3
// 595.758 us; speedup vs baseline: 4.7218x; 1.3671x over previous
//
#include <hip/hip_runtime.h>
#include <hip/hip_bf16.h>
#include <math.h>

#define D 128
#define LRELU_SLOPE 0.2f

typedef __attribute__((ext_vector_type(8))) short bf16x8;
typedef __attribute__((ext_vector_type(4))) float f32x4;

__device__ __forceinline__ float lrelu(float x){ return x > 0.f ? x : LRELU_SLOPE * x; }

__device__ __forceinline__ unsigned short bf16_rn(float x){
  unsigned int u = __float_as_uint(x);
  return (unsigned short)((u + 0x7FFFu + ((u >> 16) & 1u)) >> 16);
}

// ---------------- CSR build (dst-indexed) ----------------
__global__ void count_kernel(const int* __restrict__ dst, int E, int* __restrict__ counts){
  int e = blockIdx.x*blockDim.x + threadIdx.x;
  if (e < E) atomicAdd(&counts[dst[e]], 1);
}

// Phase 1: per-block LDS scan of 1024-element chunks.
__global__ __launch_bounds__(1024) void scan_blocks_kernel(const int* __restrict__ counts,
    int* __restrict__ row_ptr, int* __restrict__ block_sums, int n){
  __shared__ int s[1024];
  int t = threadIdx.x;
  int i = blockIdx.x*1024 + t;
  int v = (i < n) ? counts[i] : 0;
  s[t] = v;
  __syncthreads();
  #pragma unroll
  for (int d = 1; d < 1024; d <<= 1){
    int add = (t >= d) ? s[t-d] : 0;
    __syncthreads();
    s[t] += add;
    __syncthreads();
  }
  if (i < n) row_ptr[i] = s[t] - v;       // local exclusive prefix
  if (t == 1023) block_sums[blockIdx.x] = s[1023];
}

// Phase 2: single-block scan of block sums (nb <= 1024).
__global__ __launch_bounds__(1024) void scan_top_kernel(const int* __restrict__ block_sums,
    int* __restrict__ block_off, int* __restrict__ row_ptr, int nb, int n){
  __shared__ int s[1024];
  int t = threadIdx.x;
  int v = (t < nb) ? block_sums[t] : 0;
  s[t] = v;
  __syncthreads();
  #pragma unroll
  for (int d = 1; d < 1024; d <<= 1){
    int add = (t >= d) ? s[t-d] : 0;
    __syncthreads();
    s[t] += add;
    __syncthreads();
  }
  if (t < nb) block_off[t] = s[t] - v;    // exclusive block offset
  if (t == 1023) row_ptr[n] = s[1023];    // total edge count
}

// Phase 3: add block offsets, produce final row_ptr + cursor.
__global__ __launch_bounds__(1024) void scan_add_kernel(int* __restrict__ row_ptr,
    int* __restrict__ cursor, const int* __restrict__ block_off, int n){
  int i = blockIdx.x*1024 + threadIdx.x;
  if (i < n){
    int r = row_ptr[i] + block_off[blockIdx.x];
    row_ptr[i] = r;
    cursor[i]  = r;
  }
}

__global__ void scatter_kernel(const int* __restrict__ src, const int* __restrict__ dst,
                               int E, int* __restrict__ cursor, int* __restrict__ col){
  int e = blockIdx.x*blockDim.x + threadIdx.x;
  if (e < E){
    int d = dst[e];
    int pos = atomicAdd(&cursor[d], 1);
    col[pos] = src[e];
  }
}

// ---------------- MFMA bf16 split-precision GEMM + attention logits ----------------
// H = X @ W (M=n rows, N=K=128), 3-term split: xh*wh + xl*wh + xh*wl  (~fp32 accurate)
// Block: 256 threads (4 waves). Tile: 128 rows x 128 cols, full K=128 staged in LDS.
// LDS layout: [row][128] bf16, XOR-swizzled in 8-element (16B) groups:
//   element (r,c) stored at group ((c>>3) ^ (r&7)), giving conflict-free ds_read_b128.
__global__ __launch_bounds__(256) void gemm_al_kernel(const float* __restrict__ X,
    const float* __restrict__ W, const float* __restrict__ a_src, const float* __restrict__ a_dst,
    float* __restrict__ H, float* __restrict__ ALs, float* __restrict__ ALd, int n)
{
  __shared__ unsigned short Xh[128*128];   // 32 KB
  __shared__ unsigned short Xl[128*128];   // 32 KB
  __shared__ unsigned short Wh[128*128];   // 32 KB (W transposed: [n][k])
  __shared__ unsigned short Wl[128*128];   // 32 KB
  int tid  = threadIdx.x;
  int lane = tid & 63;
  int wave = tid >> 6;
  int row0 = blockIdx.x * 128;

  // ---- stage W: read row-major W[k][n], write transposed+split+swizzled Wt[n][k] ----
  {
    int nn   = tid & 127;
    int half = tid >> 7;           // 0..1
    int swz  = nn & 7;
    #pragma unroll 4
    for (int kk = 0; kk < 64; ++kk){
      int k = half*64 + kk;
      float w = W[k*D + nn];       // lanes: consecutive nn, same k -> coalesced
      unsigned short h = bf16_rn(w);
      float wh = __uint_as_float(((unsigned int)h) << 16);
      unsigned short l = bf16_rn(w - wh);
      int idx = nn*128 + (((k>>3) ^ swz) << 3) + (k & 7);
      Wh[idx] = h; Wl[idx] = l;
    }
  }
  // ---- stage X tile: coalesced float4 reads, split, swizzled packed writes ----
  {
    #pragma unroll 4
    for (int it = 0; it < 16; ++it){
      int f  = it*256 + tid;       // 0..4095
      int r  = f >> 5;             // 0..127
      int c4 = f & 31;             // float4 index within row
      float4 v = make_float4(0.f,0.f,0.f,0.f);
      int gr = row0 + r;
      if (gr < n) v = ((const float4*)(X + (size_t)gr*D))[c4];
      unsigned short h0 = bf16_rn(v.x);
      unsigned short h1 = bf16_rn(v.y);
      unsigned short h2 = bf16_rn(v.z);
      unsigned short h3 = bf16_rn(v.w);
      unsigned short l0 = bf16_rn(v.x - __uint_as_float(((unsigned)h0)<<16));
      unsigned short l1 = bf16_rn(v.y - __uint_as_float(((unsigned)h1)<<16));
      unsigned short l2 = bf16_rn(v.z - __uint_as_float(((unsigned)h2)<<16));
      unsigned short l3 = bf16_rn(v.w - __uint_as_float(((unsigned)h3)<<16));
      int g   = (c4 >> 1) ^ (r & 7);
      int idx = r*128 + (g << 3) + ((c4 & 1) << 2);
      *(uint2*)&Xh[idx] = make_uint2((unsigned)h0 | ((unsigned)h1<<16),
                                     (unsigned)h2 | ((unsigned)h3<<16));
      *(uint2*)&Xl[idx] = make_uint2((unsigned)l0 | ((unsigned)l1<<16),
                                     (unsigned)l2 | ((unsigned)l3<<16));
    }
  }
  __syncthreads();

  int l15 = lane & 15;
  int l4  = lane >> 4;

  f32x4 acc[2][8];
  #pragma unroll
  for (int rf = 0; rf < 2; ++rf)
    #pragma unroll
    for (int cf = 0; cf < 8; ++cf)
      acc[rf][cf] = (f32x4){0.f, 0.f, 0.f, 0.f};

  #pragma unroll
  for (int kc = 0; kc < 4; ++kc){
    int g = kc*4 + l4;             // k-group 0..15 for this lane
    bf16x8 ah[2], al[2];
    #pragma unroll
    for (int rf = 0; rf < 2; ++rf){
      int r   = wave*32 + rf*16 + l15;
      int idx = r*128 + ((g ^ (r & 7)) << 3);
      ah[rf] = *(const bf16x8*)&Xh[idx];
      al[rf] = *(const bf16x8*)&Xl[idx];
    }
    #pragma unroll
    for (int cf = 0; cf < 8; ++cf){
      int nn  = cf*16 + l15;
      int idx = nn*128 + ((g ^ (nn & 7)) << 3);
      bf16x8 bh = *(const bf16x8*)&Wh[idx];
      bf16x8 bl = *(const bf16x8*)&Wl[idx];
      #pragma unroll
      for (int rf = 0; rf < 2; ++rf){
        acc[rf][cf] = __builtin_amdgcn_mfma_f32_16x16x32_bf16(ah[rf], bh, acc[rf][cf], 0, 0, 0);
        acc[rf][cf] = __builtin_amdgcn_mfma_f32_16x16x32_bf16(al[rf], bh, acc[rf][cf], 0, 0, 0);
        acc[rf][cf] = __builtin_amdgcn_mfma_f32_16x16x32_bf16(ah[rf], bl, acc[rf][cf], 0, 0, 0);
      }
    }
  }

  // ---- epilogue: store H + attention logits ----
  float as_c[8], ad_c[8];
  #pragma unroll
  for (int cf = 0; cf < 8; ++cf){
    as_c[cf] = a_src[cf*16 + l15];
    ad_c[cf] = a_dst[cf*16 + l15];
  }

  #pragma unroll
  for (int rf = 0; rf < 2; ++rf){
    #pragma unroll
    for (int reg = 0; reg < 4; ++reg){
      int gr = row0 + wave*32 + rf*16 + l4*4 + reg;   // C/D: row=(lane>>4)*4+reg
      bool ok = gr < n;
      if (ok){
        #pragma unroll
        for (int cf = 0; cf < 8; ++cf)
          H[(size_t)gr*D + cf*16 + l15] = acc[rf][cf][reg];  // col = lane&15
      }
      float ps = 0.f, pd = 0.f;
      #pragma unroll
      for (int cf = 0; cf < 8; ++cf){
        ps += acc[rf][cf][reg] * as_c[cf];
        pd += acc[rf][cf][reg] * ad_c[cf];
      }
      ps += __shfl_xor(ps, 1); pd += __shfl_xor(pd, 1);
      ps += __shfl_xor(ps, 2); pd += __shfl_xor(pd, 2);
      ps += __shfl_xor(ps, 4); pd += __shfl_xor(pd, 4);
      ps += __shfl_xor(ps, 8); pd += __shfl_xor(pd, 8);
      if (l15 == 0 && ok){ ALs[gr] = ps; ALd[gr] = pd; }
    }
  }
}

// ---------------- per-dst online-softmax aggregation ----------------
__global__ __launch_bounds__(256) void agg_kernel(const float* __restrict__ H,
    const float* __restrict__ ALs, const float* __restrict__ ALd,
    const int* __restrict__ row_ptr, const int* __restrict__ col,
    const float* __restrict__ bias, float* __restrict__ out, int n)
{
  int gtid = blockIdx.x*blockDim.x + threadIdx.x;
  int node = gtid >> 6;
  int lane = gtid & 63;
  if (node >= n) return;

  int beg = row_ptr[node], end = row_ptr[node+1];
  float ald = ALd[node];
  const float2* H2 = (const float2*)H;

  float2 acc = H2[(size_t)node*64 + lane];   // self-loop h[i]
  float m = lrelu(ALs[node] + ald);          // e_self
  float z = 1.f;

  int s_next = (beg < end) ? col[beg] : 0;
  for (int j = beg; j < end; ++j){
    int s = s_next;
    if (j+1 < end) s_next = col[j+1];
    float e = lrelu(ALs[s] + ald);
    float2 hs = H2[(size_t)s*64 + lane];
    float w;
    if (e > m){                       // wave-uniform branch (scalar state)
      float sc = __expf(m - e);
      z *= sc; acc.x *= sc; acc.y *= sc;
      m = e; w = 1.f;
    } else {
      w = __expf(e - m);
    }
    z += w;
    acc.x += w*hs.x; acc.y += w*hs.y;
  }
  float inv = 1.f / z;
  float2 b2 = ((const float2*)bias)[lane];
  float2 o; o.x = acc.x*inv + b2.x; o.y = acc.y*inv + b2.y;
  ((float2*)out)[(size_t)node*64 + lane] = o;
}

// ---------------- launch ----------------
extern "C" void kernel_launch(void* const* d_in, const int* in_sizes, int n_in,
                              void* d_out, int out_size, void* d_ws, size_t ws_size,
                              hipStream_t stream)
{
  const float* x   = (const float*)d_in[0];
  const int*   ei  = (const int*)  d_in[1];
  const float* W1  = (const float*)d_in[2];
  const float* as1 = (const float*)d_in[3];
  const float* ad1 = (const float*)d_in[4];
  const float* b1  = (const float*)d_in[5];
  const float* W2  = (const float*)d_in[6];
  const float* as2 = (const float*)d_in[7];
  const float* ad2 = (const float*)d_in[8];
  const float* b2  = (const float*)d_in[9];

  int n = in_sizes[0] / D;
  int E = in_sizes[1] / 2;
  const int* src = ei;
  const int* dst = ei + E;

  // workspace layout
  float* h   = (float*)d_ws;                 // n*D
  float* als = h + (size_t)n*D;              // n
  float* ald = als + n;                      // n
  int* row_ptr = (int*)(ald + n);            // n+1
  int* cursor  = row_ptr + (n+1);            // n
  int* counts  = cursor + n;                 // n
  int* block_sums = counts + n;              // 1024
  int* block_off  = block_sums + 1024;       // 1024
  int* col     = block_off + 1024;           // E

  float* out = (float*)d_out;

  hipMemsetAsync(counts, 0, (size_t)n*sizeof(int), stream);
  int eb = (E + 255)/256;
  int nb = (n + 1023)/1024;
  count_kernel      <<<eb, 256, 0, stream>>>(dst, E, counts);
  scan_blocks_kernel<<<nb, 1024, 0, stream>>>(counts, row_ptr, block_sums, n);
  scan_top_kernel   <<<1, 1024, 0, stream>>>(block_sums, block_off, row_ptr, nb, n);
  scan_add_kernel   <<<nb, 1024, 0, stream>>>(row_ptr, cursor, block_off, n);
  scatter_kernel    <<<eb, 256, 0, stream>>>(src, dst, E, cursor, col);

  int ntiles = (n + 127)/128;
  int aggblocks = (int)(((size_t)n*64 + 255)/256);

  gemm_al_kernel<<<ntiles, 256, 0, stream>>>(x,  W1, as1, ad1, h, als, ald, n);
  agg_kernel    <<<aggblocks, 256, 0, stream>>>(h, als, ald, row_ptr, col, b1, out, n);
  gemm_al_kernel<<<ntiles, 256, 0, stream>>>(out, W2, as2, ad2, h, als, ald, n);
  agg_kernel    <<<aggblocks, 256, 0, stream>>>(h, als, ald, row_ptr, col, b2, out, n);
}

// Round 4
// 492.629 us; speedup vs baseline: 5.7102x; 1.2093x over previous
//
#include <hip/hip_runtime.h>
#include <hip/hip_bf16.h>
#include <math.h>

#define D 128
#define LRELU_SLOPE 0.2f

typedef __attribute__((ext_vector_type(8))) short bf16x8;
typedef __attribute__((ext_vector_type(4))) float f32x4;

__device__ __forceinline__ float lrelu(float x){ return x > 0.f ? x : LRELU_SLOPE * x; }

__device__ __forceinline__ unsigned short bf16_rn(float x){
  unsigned int u = __float_as_uint(x);
  return (unsigned short)((u + 0x7FFFu + ((u >> 16) & 1u)) >> 16);
}
__device__ __forceinline__ float bf16_lo_f(unsigned int u){ return __uint_as_float(u << 16); }
__device__ __forceinline__ float bf16_hi_f(unsigned int u){ return __uint_as_float(u & 0xFFFF0000u); }

// ---------------- CSR build (dst-indexed) ----------------
__global__ void count_kernel(const int* __restrict__ dst, int E, int* __restrict__ counts){
  int e = blockIdx.x*blockDim.x + threadIdx.x;
  if (e < E) atomicAdd(&counts[dst[e]], 1);
}

__global__ __launch_bounds__(1024) void scan_blocks_kernel(const int* __restrict__ counts,
    int* __restrict__ row_ptr, int* __restrict__ block_sums, int n){
  __shared__ int s[1024];
  int t = threadIdx.x;
  int i = blockIdx.x*1024 + t;
  int v = (i < n) ? counts[i] : 0;
  s[t] = v;
  __syncthreads();
  #pragma unroll
  for (int d = 1; d < 1024; d <<= 1){
    int add = (t >= d) ? s[t-d] : 0;
    __syncthreads();
    s[t] += add;
    __syncthreads();
  }
  if (i < n) row_ptr[i] = s[t] - v;
  if (t == 1023) block_sums[blockIdx.x] = s[1023];
}

__global__ __launch_bounds__(1024) void scan_top_kernel(const int* __restrict__ block_sums,
    int* __restrict__ block_off, int* __restrict__ row_ptr, int nb, int n){
  __shared__ int s[1024];
  int t = threadIdx.x;
  int v = (t < nb) ? block_sums[t] : 0;
  s[t] = v;
  __syncthreads();
  #pragma unroll
  for (int d = 1; d < 1024; d <<= 1){
    int add = (t >= d) ? s[t-d] : 0;
    __syncthreads();
    s[t] += add;
    __syncthreads();
  }
  if (t < nb) block_off[t] = s[t] - v;
  if (t == 1023) row_ptr[n] = s[1023];
}

__global__ __launch_bounds__(1024) void scan_add_kernel(int* __restrict__ row_ptr,
    int* __restrict__ cursor, const int* __restrict__ block_off, int n){
  int i = blockIdx.x*1024 + threadIdx.x;
  if (i < n){
    int r = row_ptr[i] + block_off[blockIdx.x];
    row_ptr[i] = r;
    cursor[i]  = r;
  }
}

__global__ void scatter_kernel(const int* __restrict__ src, const int* __restrict__ dst,
                               int E, int* __restrict__ cursor, int* __restrict__ col){
  int e = blockIdx.x*blockDim.x + threadIdx.x;
  if (e < E){
    int d = dst[e];
    int pos = atomicAdd(&cursor[d], 1);
    col[pos] = src[e];
  }
}

// ---------------- W pre-split: fp32 W[k][n] -> bf16 hi/lo, transposed [n][k], swizzled ----
__global__ __launch_bounds__(256) void wsplit_kernel(const float* __restrict__ W,
    unsigned short* __restrict__ Wh, unsigned short* __restrict__ Wl){
  int t = blockIdx.x*256 + threadIdx.x;   // 0..16383
  int k  = t >> 7;
  int nn = t & 127;
  float w = W[t];                          // coalesced
  unsigned short h = bf16_rn(w);
  float whf = __uint_as_float(((unsigned int)h) << 16);
  unsigned short l = bf16_rn(w - whf);
  int idx = nn*128 + (((k>>3) ^ (nn&7)) << 3) + (k & 7);
  Wh[idx] = h; Wl[idx] = l;
}

// ---------------- MFMA bf16 split-precision GEMM + attention logits ----------------
// H = X @ W, 3-term split: xh*wh + xl*wh + xh*wl. H output in bf16.
// Block: 256 threads (4 waves). Tile: 128 rows x 128 cols, K=128 staged in LDS.
// LDS swizzle: element (r,c) at 8-group ((c>>3) ^ (r&7)) -> conflict-free ds_read_b128.
__global__ __launch_bounds__(256) void gemm_al_kernel(const float* __restrict__ X,
    const unsigned short* __restrict__ Wgh, const unsigned short* __restrict__ Wgl,
    const float* __restrict__ a_src, const float* __restrict__ a_dst,
    unsigned short* __restrict__ Hb, float* __restrict__ ALs, float* __restrict__ ALd, int n)
{
  __shared__ unsigned short Xh[128*128];
  __shared__ unsigned short Xl[128*128];
  __shared__ unsigned short Wh[128*128];
  __shared__ unsigned short Wl[128*128];
  int tid  = threadIdx.x;
  int lane = tid & 63;
  int wave = tid >> 6;
  int row0 = blockIdx.x * 128;

  // ---- stage W: plain wide copy of pre-split, pre-swizzled data ----
  #pragma unroll
  for (int i = 0; i < 8; ++i){
    int idx = i*256 + tid;                 // 2048 uint4 per array
    ((uint4*)Wh)[idx] = ((const uint4*)Wgh)[idx];
    ((uint4*)Wl)[idx] = ((const uint4*)Wgl)[idx];
  }
  // ---- stage X tile: coalesced float4 reads, split, swizzled packed writes ----
  #pragma unroll 4
  for (int it = 0; it < 16; ++it){
    int f  = it*256 + tid;
    int r  = f >> 5;
    int c4 = f & 31;
    float4 v = make_float4(0.f,0.f,0.f,0.f);
    int gr = row0 + r;
    if (gr < n) v = ((const float4*)(X + (size_t)gr*D))[c4];
    unsigned short h0 = bf16_rn(v.x);
    unsigned short h1 = bf16_rn(v.y);
    unsigned short h2 = bf16_rn(v.z);
    unsigned short h3 = bf16_rn(v.w);
    unsigned short l0 = bf16_rn(v.x - __uint_as_float(((unsigned)h0)<<16));
    unsigned short l1 = bf16_rn(v.y - __uint_as_float(((unsigned)h1)<<16));
    unsigned short l2 = bf16_rn(v.z - __uint_as_float(((unsigned)h2)<<16));
    unsigned short l3 = bf16_rn(v.w - __uint_as_float(((unsigned)h3)<<16));
    int g   = (c4 >> 1) ^ (r & 7);
    int idx = r*128 + (g << 3) + ((c4 & 1) << 2);
    *(uint2*)&Xh[idx] = make_uint2((unsigned)h0 | ((unsigned)h1<<16),
                                   (unsigned)h2 | ((unsigned)h3<<16));
    *(uint2*)&Xl[idx] = make_uint2((unsigned)l0 | ((unsigned)l1<<16),
                                   (unsigned)l2 | ((unsigned)l3<<16));
  }
  __syncthreads();

  int l15 = lane & 15;
  int l4  = lane >> 4;

  f32x4 acc[2][8];
  #pragma unroll
  for (int rf = 0; rf < 2; ++rf)
    #pragma unroll
    for (int cf = 0; cf < 8; ++cf)
      acc[rf][cf] = (f32x4){0.f, 0.f, 0.f, 0.f};

  #pragma unroll
  for (int kc = 0; kc < 4; ++kc){
    int g = kc*4 + l4;
    bf16x8 ah[2], al[2];
    #pragma unroll
    for (int rf = 0; rf < 2; ++rf){
      int r   = wave*32 + rf*16 + l15;
      int idx = r*128 + ((g ^ (r & 7)) << 3);
      ah[rf] = *(const bf16x8*)&Xh[idx];
      al[rf] = *(const bf16x8*)&Xl[idx];
    }
    #pragma unroll
    for (int cf = 0; cf < 8; ++cf){
      int nn  = cf*16 + l15;
      int idx = nn*128 + ((g ^ (nn & 7)) << 3);
      bf16x8 bh = *(const bf16x8*)&Wh[idx];
      bf16x8 bl = *(const bf16x8*)&Wl[idx];
      #pragma unroll
      for (int rf = 0; rf < 2; ++rf){
        acc[rf][cf] = __builtin_amdgcn_mfma_f32_16x16x32_bf16(ah[rf], bh, acc[rf][cf], 0, 0, 0);
        acc[rf][cf] = __builtin_amdgcn_mfma_f32_16x16x32_bf16(al[rf], bh, acc[rf][cf], 0, 0, 0);
        acc[rf][cf] = __builtin_amdgcn_mfma_f32_16x16x32_bf16(ah[rf], bl, acc[rf][cf], 0, 0, 0);
      }
    }
  }

  // ---- epilogue: store H (bf16) + attention logits (fp32) ----
  float as_c[8], ad_c[8];
  #pragma unroll
  for (int cf = 0; cf < 8; ++cf){
    as_c[cf] = a_src[cf*16 + l15];
    ad_c[cf] = a_dst[cf*16 + l15];
  }

  #pragma unroll
  for (int rf = 0; rf < 2; ++rf){
    #pragma unroll
    for (int reg = 0; reg < 4; ++reg){
      int gr = row0 + wave*32 + rf*16 + l4*4 + reg;   // C/D: row=(lane>>4)*4+reg
      bool ok = gr < n;
      if (ok){
        #pragma unroll
        for (int cf = 0; cf < 8; ++cf)
          Hb[(size_t)gr*D + cf*16 + l15] = bf16_rn(acc[rf][cf][reg]);  // col = lane&15
      }
      float ps = 0.f, pd = 0.f;
      #pragma unroll
      for (int cf = 0; cf < 8; ++cf){
        ps += acc[rf][cf][reg] * as_c[cf];
        pd += acc[rf][cf][reg] * ad_c[cf];
      }
      ps += __shfl_xor(ps, 1); pd += __shfl_xor(pd, 1);
      ps += __shfl_xor(ps, 2); pd += __shfl_xor(pd, 2);
      ps += __shfl_xor(ps, 4); pd += __shfl_xor(pd, 4);
      ps += __shfl_xor(ps, 8); pd += __shfl_xor(pd, 8);
      if (l15 == 0 && ok){ ALs[gr] = ps; ALd[gr] = pd; }
    }
  }
}

// ---------------- per-dst two-phase softmax aggregation (bf16 h gathers) ----------------
__global__ __launch_bounds__(256) void agg_kernel(const unsigned short* __restrict__ Hb,
    const float* __restrict__ ALs, const float* __restrict__ ALd,
    const int* __restrict__ row_ptr, const int* __restrict__ col,
    const float* __restrict__ bias, float* __restrict__ out, int n)
{
  int gtid = blockIdx.x*blockDim.x + threadIdx.x;
  int node = gtid >> 6;
  int lane = gtid & 63;
  if (node >= n) return;

  int beg = row_ptr[node], end = row_ptr[node+1];
  float ald = ALd[node];
  float e_self = lrelu(ALs[node] + ald);

  // Phase A: true max, lane-parallel gathers + wave max-reduce
  float m = e_self;
  for (int j0 = beg; j0 < end; j0 += 64){
    int j = j0 + lane;
    float e = -1e30f;
    if (j < end) e = lrelu(ALs[col[j]] + ald);
    #pragma unroll
    for (int off = 32; off >= 1; off >>= 1)
      e = fmaxf(e, __shfl_xor(e, off));
    m = fmaxf(m, e);
  }

  // Phase B: branch-free accumulate, unroll-4 independent gather chains
  const unsigned int* H2 = (const unsigned int*)Hb;
  float w_self = __expf(e_self - m);
  unsigned int us = H2[node*64 + lane];
  float2 acc; acc.x = w_self * bf16_lo_f(us); acc.y = w_self * bf16_hi_f(us);
  float z = w_self;

  int j = beg;
  for (; j + 4 <= end; j += 4){
    int s0 = col[j], s1 = col[j+1], s2 = col[j+2], s3 = col[j+3];
    float w0 = __expf(lrelu(ALs[s0] + ald) - m);
    float w1 = __expf(lrelu(ALs[s1] + ald) - m);
    float w2 = __expf(lrelu(ALs[s2] + ald) - m);
    float w3 = __expf(lrelu(ALs[s3] + ald) - m);
    unsigned int u0 = H2[s0*64 + lane];
    unsigned int u1 = H2[s1*64 + lane];
    unsigned int u2 = H2[s2*64 + lane];
    unsigned int u3 = H2[s3*64 + lane];
    z += (w0 + w1) + (w2 + w3);
    acc.x += w0*bf16_lo_f(u0); acc.y += w0*bf16_hi_f(u0);
    acc.x += w1*bf16_lo_f(u1); acc.y += w1*bf16_hi_f(u1);
    acc.x += w2*bf16_lo_f(u2); acc.y += w2*bf16_hi_f(u2);
    acc.x += w3*bf16_lo_f(u3); acc.y += w3*bf16_hi_f(u3);
  }
  for (; j < end; ++j){
    int s = col[j];
    float w = __expf(lrelu(ALs[s] + ald) - m);
    unsigned int u = H2[s*64 + lane];
    z += w;
    acc.x += w*bf16_lo_f(u); acc.y += w*bf16_hi_f(u);
  }

  float inv = 1.f / z;
  float2 b2 = ((const float2*)bias)[lane];
  float2 o; o.x = acc.x*inv + b2.x; o.y = acc.y*inv + b2.y;
  ((float2*)out)[node*64 + lane] = o;
}

// ---------------- launch ----------------
extern "C" void kernel_launch(void* const* d_in, const int* in_sizes, int n_in,
                              void* d_out, int out_size, void* d_ws, size_t ws_size,
                              hipStream_t stream)
{
  const float* x   = (const float*)d_in[0];
  const int*   ei  = (const int*)  d_in[1];
  const float* W1  = (const float*)d_in[2];
  const float* as1 = (const float*)d_in[3];
  const float* ad1 = (const float*)d_in[4];
  const float* b1  = (const float*)d_in[5];
  const float* W2  = (const float*)d_in[6];
  const float* as2 = (const float*)d_in[7];
  const float* ad2 = (const float*)d_in[8];
  const float* b2  = (const float*)d_in[9];

  int n = in_sizes[0] / D;
  int E = in_sizes[1] / 2;
  const int* src = ei;
  const int* dst = ei + E;

  // workspace layout
  unsigned short* hb = (unsigned short*)d_ws;          // n*128 bf16 (25.6 MB)
  float* als = (float*)(hb + (size_t)n*D);             // n
  float* ald = als + n;                                // n
  int* row_ptr = (int*)(ald + n);                      // n+1
  int* cursor  = row_ptr + (n+1);                      // n
  int* counts  = cursor + n;                           // n
  int* block_sums = counts + n;                        // 1024
  int* block_off  = block_sums + 1024;                 // 1024
  unsigned short* wh1 = (unsigned short*)(block_off + 1024);  // 16384
  unsigned short* wl1 = wh1 + 16384;
  unsigned short* wh2 = wl1 + 16384;
  unsigned short* wl2 = wh2 + 16384;
  int* col = (int*)(wl2 + 16384);                      // E

  float* out = (float*)d_out;

  hipMemsetAsync(counts, 0, (size_t)n*sizeof(int), stream);
  int eb = (E + 255)/256;
  int nb = (n + 1023)/1024;
  count_kernel      <<<eb, 256, 0, stream>>>(dst, E, counts);
  wsplit_kernel     <<<64, 256, 0, stream>>>(W1, wh1, wl1);
  wsplit_kernel     <<<64, 256, 0, stream>>>(W2, wh2, wl2);
  scan_blocks_kernel<<<nb, 1024, 0, stream>>>(counts, row_ptr, block_sums, n);
  scan_top_kernel   <<<1, 1024, 0, stream>>>(block_sums, block_off, row_ptr, nb, n);
  scan_add_kernel   <<<nb, 1024, 0, stream>>>(row_ptr, cursor, block_off, n);
  scatter_kernel    <<<eb, 256, 0, stream>>>(src, dst, E, cursor, col);

  int ntiles = (n + 127)/128;
  int aggblocks = (int)(((size_t)n*64 + 255)/256);

  gemm_al_kernel<<<ntiles, 256, 0, stream>>>(x,  wh1, wl1, as1, ad1, hb, als, ald, n);
  agg_kernel    <<<aggblocks, 256, 0, stream>>>(hb, als, ald, row_ptr, col, b1, out, n);
  gemm_al_kernel<<<ntiles, 256, 0, stream>>>(out, wh2, wl2, as2, ad2, hb, als, ald, n);
  agg_kernel    <<<aggblocks, 256, 0, stream>>>(hb, als, ald, row_ptr, col, b2, out, n);
}

// Round 5
// 350.383 us; speedup vs baseline: 8.0284x; 1.4060x over previous
//
#include <hip/hip_runtime.h>
#include <hip/hip_bf16.h>
#include <math.h>

#define D 128
#define LRELU_SLOPE 0.2f
#define BSH 9
#define BSZ 512
#define SC_CHUNK 16384

typedef __attribute__((ext_vector_type(8))) short bf16x8;
typedef __attribute__((ext_vector_type(4))) float f32x4;

__device__ __forceinline__ float lrelu(float x){ return x > 0.f ? x : LRELU_SLOPE * x; }

__device__ __forceinline__ unsigned short bf16_rn(float x){
  unsigned int u = __float_as_uint(x);
  return (unsigned short)((u + 0x7FFFu + ((u >> 16) & 1u)) >> 16);
}
__device__ __forceinline__ float bf16_lo_f(unsigned int u){ return __uint_as_float(u << 16); }
__device__ __forceinline__ float bf16_hi_f(unsigned int u){ return __uint_as_float(u & 0xFFFF0000u); }

// ---------------- bucketed CSR build ----------------
// Buckets of 512 consecutive dst nodes. nbuck = ceil(n/512) <= 256.

__global__ __launch_bounds__(1024) void bucket_count_kernel(const int* __restrict__ dst, int E,
    int* __restrict__ bcnt, int nbuck){
  __shared__ int h[256];
  int t = threadIdx.x;
  if (t < 256) h[t] = 0;
  __syncthreads();
  for (int e = blockIdx.x*1024 + t; e < E; e += gridDim.x*1024)
    atomicAdd(&h[dst[e] >> BSH], 1);
  __syncthreads();
  if (t < nbuck && h[t]) atomicAdd(&bcnt[t], h[t]);
}

__global__ __launch_bounds__(256) void bucket_scan_kernel(const int* __restrict__ bcnt,
    int* __restrict__ bbase, int* __restrict__ bcur, int nbuck, int E){
  __shared__ int s[256];
  int t = threadIdx.x;
  int v = (t < nbuck) ? bcnt[t] : 0;
  s[t] = v;
  __syncthreads();
  #pragma unroll
  for (int d = 1; d < 256; d <<= 1){
    int add = (t >= d) ? s[t-d] : 0;
    __syncthreads();
    s[t] += add;
    __syncthreads();
  }
  if (t < nbuck){ int b = s[t] - v; bbase[t] = b; bcur[t] = b; }
  if (t == 0) bbase[nbuck] = E;
}

// Each block: LDS histogram of its chunk -> one global chunk reservation per bucket ->
// contiguous packed writes per (block,bucket) run. packed = (src<<9) | (dst&511).
__global__ __launch_bounds__(1024) void bucket_scatter_kernel(const int* __restrict__ src,
    const int* __restrict__ dst, int E, int* __restrict__ bcur,
    unsigned int* __restrict__ ebuf, int nbuck){
  __shared__ int h[256];
  __shared__ int cb[256];
  int t = threadIdx.x;
  int base = blockIdx.x * SC_CHUNK;
  int end = base + SC_CHUNK; if (end > E) end = E;
  if (t < 256) h[t] = 0;
  __syncthreads();
  for (int e = base + t; e < end; e += 1024)
    atomicAdd(&h[dst[e] >> BSH], 1);
  __syncthreads();
  if (t < nbuck){
    cb[t] = h[t] ? atomicAdd(&bcur[t], h[t]) : 0;
    h[t] = 0;                       // reuse as local cursor
  }
  __syncthreads();
  for (int e = base + t; e < end; e += 1024){
    int d = dst[e];
    int b = d >> BSH;
    int lpos = atomicAdd(&h[b], 1);
    ebuf[cb[b] + lpos] = ((unsigned int)src[e] << BSH) | (unsigned int)(d & (BSZ-1));
  }
}

// One block per bucket: LDS count[512] -> LDS scan -> row_ptr; then scatter col
// within the bucket's contiguous (L2-resident) region.
__global__ __launch_bounds__(256) void bucket_csr_kernel(const unsigned int* __restrict__ ebuf,
    const int* __restrict__ bbase, int* __restrict__ row_ptr, int* __restrict__ col,
    int n, int nbuck){
  __shared__ int c[512];
  __shared__ int ps[256];
  int b = blockIdx.x;
  int t = threadIdx.x;
  int base = bbase[b], end = bbase[b+1];
  c[t] = 0; c[t+256] = 0;
  __syncthreads();
  for (int i = base + t; i < end; i += 256)
    atomicAdd(&c[ebuf[i] & (BSZ-1)], 1);
  __syncthreads();
  int a0 = c[2*t], a1 = c[2*t+1];
  int pair = a0 + a1;
  ps[t] = pair;
  __syncthreads();
  #pragma unroll
  for (int d = 1; d < 256; d <<= 1){
    int add = (t >= d) ? ps[t-d] : 0;
    __syncthreads();
    ps[t] += add;
    __syncthreads();
  }
  int excl = ps[t] - pair;
  __syncthreads();
  int lo = b << BSH;
  int g0 = lo + 2*t, g1 = g0 + 1;
  if (g0 < n) row_ptr[g0] = base + excl;
  if (g1 < n) row_ptr[g1] = base + excl + a0;
  c[2*t]   = excl;                  // cursors (local offsets)
  c[2*t+1] = excl + a0;
  __syncthreads();
  for (int i = base + t; i < end; i += 256){
    unsigned int p = ebuf[i];
    int dlo = p & (BSZ-1);
    int pos = base + atomicAdd(&c[dlo], 1);
    col[pos] = (int)(p >> BSH);
  }
  if (b == 0 && t == 0) row_ptr[n] = bbase[nbuck];
}

// ---------------- W pre-split: fp32 W[k][n] -> bf16 hi/lo, transposed [n][k], swizzled ----
__global__ __launch_bounds__(256) void wsplit_kernel(const float* __restrict__ W,
    unsigned short* __restrict__ Wh, unsigned short* __restrict__ Wl){
  int t = blockIdx.x*256 + threadIdx.x;   // 0..16383
  int k  = t >> 7;
  int nn = t & 127;
  float w = W[t];
  unsigned short h = bf16_rn(w);
  float whf = __uint_as_float(((unsigned int)h) << 16);
  unsigned short l = bf16_rn(w - whf);
  int idx = nn*128 + (((k>>3) ^ (nn&7)) << 3) + (k & 7);
  Wh[idx] = h; Wl[idx] = l;
}

// ---------------- MFMA bf16 split-precision GEMM + attention logits ----------------
__global__ __launch_bounds__(256) void gemm_al_kernel(const float* __restrict__ X,
    const unsigned short* __restrict__ Wgh, const unsigned short* __restrict__ Wgl,
    const float* __restrict__ a_src, const float* __restrict__ a_dst,
    unsigned short* __restrict__ Hb, float* __restrict__ ALs, float* __restrict__ ALd, int n)
{
  __shared__ unsigned short Xh[128*128];
  __shared__ unsigned short Xl[128*128];
  __shared__ unsigned short Wh[128*128];
  __shared__ unsigned short Wl[128*128];
  int tid  = threadIdx.x;
  int lane = tid & 63;
  int wave = tid >> 6;
  int row0 = blockIdx.x * 128;

  #pragma unroll
  for (int i = 0; i < 8; ++i){
    int idx = i*256 + tid;
    ((uint4*)Wh)[idx] = ((const uint4*)Wgh)[idx];
    ((uint4*)Wl)[idx] = ((const uint4*)Wgl)[idx];
  }
  #pragma unroll 4
  for (int it = 0; it < 16; ++it){
    int f  = it*256 + tid;
    int r  = f >> 5;
    int c4 = f & 31;
    float4 v = make_float4(0.f,0.f,0.f,0.f);
    int gr = row0 + r;
    if (gr < n) v = ((const float4*)(X + (size_t)gr*D))[c4];
    unsigned short h0 = bf16_rn(v.x);
    unsigned short h1 = bf16_rn(v.y);
    unsigned short h2 = bf16_rn(v.z);
    unsigned short h3 = bf16_rn(v.w);
    unsigned short l0 = bf16_rn(v.x - __uint_as_float(((unsigned)h0)<<16));
    unsigned short l1 = bf16_rn(v.y - __uint_as_float(((unsigned)h1)<<16));
    unsigned short l2 = bf16_rn(v.z - __uint_as_float(((unsigned)h2)<<16));
    unsigned short l3 = bf16_rn(v.w - __uint_as_float(((unsigned)h3)<<16));
    int g   = (c4 >> 1) ^ (r & 7);
    int idx = r*128 + (g << 3) + ((c4 & 1) << 2);
    *(uint2*)&Xh[idx] = make_uint2((unsigned)h0 | ((unsigned)h1<<16),
                                   (unsigned)h2 | ((unsigned)h3<<16));
    *(uint2*)&Xl[idx] = make_uint2((unsigned)l0 | ((unsigned)l1<<16),
                                   (unsigned)l2 | ((unsigned)l3<<16));
  }
  __syncthreads();

  int l15 = lane & 15;
  int l4  = lane >> 4;

  f32x4 acc[2][8];
  #pragma unroll
  for (int rf = 0; rf < 2; ++rf)
    #pragma unroll
    for (int cf = 0; cf < 8; ++cf)
      acc[rf][cf] = (f32x4){0.f, 0.f, 0.f, 0.f};

  #pragma unroll
  for (int kc = 0; kc < 4; ++kc){
    int g = kc*4 + l4;
    bf16x8 ah[2], al[2];
    #pragma unroll
    for (int rf = 0; rf < 2; ++rf){
      int r   = wave*32 + rf*16 + l15;
      int idx = r*128 + ((g ^ (r & 7)) << 3);
      ah[rf] = *(const bf16x8*)&Xh[idx];
      al[rf] = *(const bf16x8*)&Xl[idx];
    }
    #pragma unroll
    for (int cf = 0; cf < 8; ++cf){
      int nn  = cf*16 + l15;
      int idx = nn*128 + ((g ^ (nn & 7)) << 3);
      bf16x8 bh = *(const bf16x8*)&Wh[idx];
      bf16x8 bl = *(const bf16x8*)&Wl[idx];
      #pragma unroll
      for (int rf = 0; rf < 2; ++rf){
        acc[rf][cf] = __builtin_amdgcn_mfma_f32_16x16x32_bf16(ah[rf], bh, acc[rf][cf], 0, 0, 0);
        acc[rf][cf] = __builtin_amdgcn_mfma_f32_16x16x32_bf16(al[rf], bh, acc[rf][cf], 0, 0, 0);
        acc[rf][cf] = __builtin_amdgcn_mfma_f32_16x16x32_bf16(ah[rf], bl, acc[rf][cf], 0, 0, 0);
      }
    }
  }

  float as_c[8], ad_c[8];
  #pragma unroll
  for (int cf = 0; cf < 8; ++cf){
    as_c[cf] = a_src[cf*16 + l15];
    ad_c[cf] = a_dst[cf*16 + l15];
  }

  #pragma unroll
  for (int rf = 0; rf < 2; ++rf){
    #pragma unroll
    for (int reg = 0; reg < 4; ++reg){
      int gr = row0 + wave*32 + rf*16 + l4*4 + reg;
      bool ok = gr < n;
      if (ok){
        #pragma unroll
        for (int cf = 0; cf < 8; ++cf)
          Hb[(size_t)gr*D + cf*16 + l15] = bf16_rn(acc[rf][cf][reg]);
      }
      float ps = 0.f, pd = 0.f;
      #pragma unroll
      for (int cf = 0; cf < 8; ++cf){
        ps += acc[rf][cf][reg] * as_c[cf];
        pd += acc[rf][cf][reg] * ad_c[cf];
      }
      ps += __shfl_xor(ps, 1); pd += __shfl_xor(pd, 1);
      ps += __shfl_xor(ps, 2); pd += __shfl_xor(pd, 2);
      ps += __shfl_xor(ps, 4); pd += __shfl_xor(pd, 4);
      ps += __shfl_xor(ps, 8); pd += __shfl_xor(pd, 8);
      if (l15 == 0 && ok){ ALs[gr] = ps; ALd[gr] = pd; }
    }
  }
}

// ---------------- per-dst two-phase softmax aggregation (bf16 h gathers) ----------------
__global__ __launch_bounds__(256) void agg_kernel(const unsigned short* __restrict__ Hb,
    const float* __restrict__ ALs, const float* __restrict__ ALd,
    const int* __restrict__ row_ptr, const int* __restrict__ col,
    const float* __restrict__ bias, float* __restrict__ out, int n)
{
  int gtid = blockIdx.x*blockDim.x + threadIdx.x;
  int node = gtid >> 6;
  int lane = gtid & 63;
  if (node >= n) return;

  int beg = row_ptr[node], end = row_ptr[node+1];
  float ald = ALd[node];
  float e_self = lrelu(ALs[node] + ald);

  float m = e_self;
  for (int j0 = beg; j0 < end; j0 += 64){
    int j = j0 + lane;
    float e = -1e30f;
    if (j < end) e = lrelu(ALs[col[j]] + ald);
    #pragma unroll
    for (int off = 32; off >= 1; off >>= 1)
      e = fmaxf(e, __shfl_xor(e, off));
    m = fmaxf(m, e);
  }

  const unsigned int* H2 = (const unsigned int*)Hb;
  float w_self = __expf(e_self - m);
  unsigned int us = H2[node*64 + lane];
  float2 acc; acc.x = w_self * bf16_lo_f(us); acc.y = w_self * bf16_hi_f(us);
  float z = w_self;

  int j = beg;
  for (; j + 4 <= end; j += 4){
    int s0 = col[j], s1 = col[j+1], s2 = col[j+2], s3 = col[j+3];
    float w0 = __expf(lrelu(ALs[s0] + ald) - m);
    float w1 = __expf(lrelu(ALs[s1] + ald) - m);
    float w2 = __expf(lrelu(ALs[s2] + ald) - m);
    float w3 = __expf(lrelu(ALs[s3] + ald) - m);
    unsigned int u0 = H2[s0*64 + lane];
    unsigned int u1 = H2[s1*64 + lane];
    unsigned int u2 = H2[s2*64 + lane];
    unsigned int u3 = H2[s3*64 + lane];
    z += (w0 + w1) + (w2 + w3);
    acc.x += w0*bf16_lo_f(u0); acc.y += w0*bf16_hi_f(u0);
    acc.x += w1*bf16_lo_f(u1); acc.y += w1*bf16_hi_f(u1);
    acc.x += w2*bf16_lo_f(u2); acc.y += w2*bf16_hi_f(u2);
    acc.x += w3*bf16_lo_f(u3); acc.y += w3*bf16_hi_f(u3);
  }
  for (; j < end; ++j){
    int s = col[j];
    float w = __expf(lrelu(ALs[s] + ald) - m);
    unsigned int u = H2[s*64 + lane];
    z += w;
    acc.x += w*bf16_lo_f(u); acc.y += w*bf16_hi_f(u);
  }

  float inv = 1.f / z;
  float2 b2 = ((const float2*)bias)[lane];
  float2 o; o.x = acc.x*inv + b2.x; o.y = acc.y*inv + b2.y;
  ((float2*)out)[node*64 + lane] = o;
}

// ---------------- launch ----------------
extern "C" void kernel_launch(void* const* d_in, const int* in_sizes, int n_in,
                              void* d_out, int out_size, void* d_ws, size_t ws_size,
                              hipStream_t stream)
{
  const float* x   = (const float*)d_in[0];
  const int*   ei  = (const int*)  d_in[1];
  const float* W1  = (const float*)d_in[2];
  const float* as1 = (const float*)d_in[3];
  const float* ad1 = (const float*)d_in[4];
  const float* b1  = (const float*)d_in[5];
  const float* W2  = (const float*)d_in[6];
  const float* as2 = (const float*)d_in[7];
  const float* ad2 = (const float*)d_in[8];
  const float* b2  = (const float*)d_in[9];

  int n = in_sizes[0] / D;
  int E = in_sizes[1] / 2;
  const int* src = ei;
  const int* dst = ei + E;
  int nbuck = (n + BSZ - 1) >> BSH;

  // workspace layout
  unsigned short* hb = (unsigned short*)d_ws;          // n*128 bf16
  float* als = (float*)(hb + (size_t)n*D);             // n
  float* ald = als + n;                                // n
  int* row_ptr = (int*)(ald + n);                      // n+1
  int* bcnt  = row_ptr + (n+1);                        // 256
  int* bbase = bcnt + 256;                             // 257
  int* bcur  = bbase + 257;                            // 256 (+pad)
  unsigned short* wh1 = (unsigned short*)(bcur + 259); // 16384 each
  unsigned short* wl1 = wh1 + 16384;
  unsigned short* wh2 = wl1 + 16384;
  unsigned short* wl2 = wh2 + 16384;
  unsigned int* ebuf = (unsigned int*)(wl2 + 16384);   // E
  int* col = (int*)(ebuf + E);                         // E

  float* out = (float*)d_out;

  hipMemsetAsync(bcnt, 0, 256*sizeof(int), stream);
  int sc_blocks = (E + SC_CHUNK - 1) / SC_CHUNK;
  bucket_count_kernel  <<<128, 1024, 0, stream>>>(dst, E, bcnt, nbuck);
  bucket_scan_kernel   <<<1, 256, 0, stream>>>(bcnt, bbase, bcur, nbuck, E);
  bucket_scatter_kernel<<<sc_blocks, 1024, 0, stream>>>(src, dst, E, bcur, ebuf, nbuck);
  bucket_csr_kernel    <<<nbuck, 256, 0, stream>>>(ebuf, bbase, row_ptr, col, n, nbuck);

  wsplit_kernel<<<64, 256, 0, stream>>>(W1, wh1, wl1);
  wsplit_kernel<<<64, 256, 0, stream>>>(W2, wh2, wl2);

  int ntiles = (n + 127)/128;
  int aggblocks = (int)(((size_t)n*64 + 255)/256);

  gemm_al_kernel<<<ntiles, 256, 0, stream>>>(x,  wh1, wl1, as1, ad1, hb, als, ald, n);
  agg_kernel    <<<aggblocks, 256, 0, stream>>>(hb, als, ald, row_ptr, col, b1, out, n);
  gemm_al_kernel<<<ntiles, 256, 0, stream>>>(out, wh2, wl2, as2, ad2, hb, als, ald, n);
  agg_kernel    <<<aggblocks, 256, 0, stream>>>(hb, als, ald, row_ptr, col, b2, out, n);
}